// Round 1
// baseline (631.925 us; speedup 1.0000x reference)
//
#include <hip/hip_runtime.h>
#include <hip/hip_bf16.h>

// ---------------------------------------------------------------------------
// Task1_bf_final_CSW2D: plane-wave beamform + 4x (conv1d over E + BN + relu)
// + dB compression.  Round 1: correctness-first f32 VALU implementation.
//
// Layouts:
//   x0   (ws)  : float  [2][P][E]   beamformed, apodized CNN input (P=32768,E=128)
//   bufA/bufB  : bf16   [8][P][E]   conv activations (raw conv+bias, pre-BN)
//   y4         : float  [P][E]      conv4 raw output (stored in bufB region)
//   BN is folded as y_norm = A*y + B with A = g*rsqrt(var+eps), B = beta - mu*A,
//   computed by k_stats from per-block partial sums emitted by each conv.
// ---------------------------------------------------------------------------

#define E_    128
#define NPIX  32768
#define NS_   (NPIX * E_)      // 4194304 elements per channel
#define NSAMP 2048

static constexpr double PI_D     = 3.14159265358979323846;
static constexpr double FS_D     = 20832000.0;
static constexpr double FDEMOD_D = 5208000.0;
static constexpr double C_D      = 1540.0;

__device__ __forceinline__ float wave_reduce_sum(float v) {
  #pragma unroll
  for (int off = 32; off; off >>= 1) v += __shfl_xor(v, off);
  return v;
}
__device__ __forceinline__ float wave_reduce_max(float v) {
  #pragma unroll
  for (int off = 32; off; off >>= 1) v = fmaxf(v, __shfl_xor(v, off));
  return v;
}

// ---------------------------------------------------------------------------
// Kernel 1: global max of (i^2 + q^2)  (nonneg -> uint-bit atomicMax is valid)
// ---------------------------------------------------------------------------
__global__ __launch_bounds__(256) void k_nrm(const float* __restrict__ id,
                                             const float* __restrict__ qd,
                                             unsigned int* __restrict__ maxsq) {
  const int total = 16 * 128 * 2048;
  float m = 0.f;
  for (int idx = blockIdx.x * 256 + threadIdx.x; idx < total; idx += gridDim.x * 256) {
    float iv = id[idx], qv = qd[idx];
    m = fmaxf(m, iv * iv + qv * qv);
  }
  m = wave_reduce_max(m);
  __shared__ float sm[4];
  if ((threadIdx.x & 63) == 0) sm[threadIdx.x >> 6] = m;
  __syncthreads();
  if (threadIdx.x == 0) {
    float mm = fmaxf(fmaxf(sm[0], sm[1]), fmaxf(sm[2], sm[3]));
    atomicMax(maxsq, __float_as_uint(mm));
  }
}

// ---------------------------------------------------------------------------
// Kernel 2: beamform.  One thread per (pixel p, element e).
// Writes apodized IQ-rotated samples into x0[c][p][e].
// ---------------------------------------------------------------------------
__global__ __launch_bounds__(256) void k_beamform(
    const float* __restrict__ idata, const float* __restrict__ qdata,
    const float* __restrict__ angles, const float* __restrict__ ele_pos,
    const float* __restrict__ time_zero, const float* __restrict__ grid,
    const unsigned int* __restrict__ maxsq, float* __restrict__ x0) {
  const int e = threadIdx.x & 127;
  const int p = blockIdx.x * 2 + (threadIdx.x >> 7);

  const float inv = 1.0f / sqrtf(__uint_as_float(*maxsq));
  const float px = grid[p * 3 + 0];
  const float pz = grid[p * 3 + 2];
  const float ang = angles[0];
  const float tz  = time_zero[0];

  constexpr float SC  = (float)(FS_D / C_D);                       // samples/m
  constexpr float TH1 = (float)(PI_D * 0.5);                       // 2pi*FDEMOD/FS (=pi/2 exactly)
  constexpr float TH2 = (float)(2.0 * PI_D * FDEMOD_D * 2.0 / C_D);// pz coefficient

  float sa, ca;
  sincosf(ang, &sa, &ca);
  const float txdel = (px * sa + pz * ca + tz * (float)C_D) * SC;

  const float ex = ele_pos[e * 3 + 0];
  const float dx = px - ex;
  const float rxdel = sqrtf(dx * dx + pz * pz) * SC;

  const float delays = txdel + rxdel;
  const float d0 = floorf(delays);
  const float frac = delays - d0;
  const int i0 = (int)d0;

  const float* isig = idata + e * NSAMP;   // event 0
  const float* qsig = qdata + e * NSAMP;
  const int c0 = min(max(i0, 0), NSAMP - 1);
  const int c1 = min(max(i0 + 1, 0), NSAMP - 1);
  const bool m0 = (i0 >= 0) && (i0 < NSAMP);
  const bool m1 = (i0 + 1 >= 0) && (i0 + 1 < NSAMP);
  const float iv0 = m0 ? isig[c0] : 0.f;
  const float iv1 = m1 ? isig[c1] : 0.f;
  const float qv0 = m0 ? qsig[c0] : 0.f;
  const float qv1 = m1 ? qsig[c1] : 0.f;
  const float ifoc = (iv0 * (1.f - frac) + iv1 * frac) * inv;
  const float qfoc = (qv0 * (1.f - frac) + qv1 * frac) * inv;

  // theta = 2pi*FDEMOD*(delays/FS - 2*pz/C), regrouped to avoid cancellation
  const float theta = delays * TH1 - pz * TH2;
  float st, ct;
  sincosf(theta, &st, &ct);
  const float ir = ifoc * ct - qfoc * st;
  const float qr = qfoc * ct + ifoc * st;

  // rx apodization (FNUM=1, MIN_W=1e-3); vz = pz
  const float ex0 = ele_pos[0];
  const float exl = ele_pos[127 * 3];
  const float avx = fabsf(dx);
  const bool mrx = (fabsf(pz) > avx) || (avx <= 0.001f) ||
                   ((dx >= 0.001f) && (px <= ex0)) ||
                   ((dx <= -0.001f) && (px >= exl));
  const float xproj = px - pz * tanf(ang);
  const bool mtx = (xproj >= ex0 * 1.2f) && (xproj <= exl * 1.2f);
  const float a = (mrx && mtx) ? 1.f : 0.f;

  const size_t base = (size_t)p * E_ + e;
  x0[base]       = ir * a;
  x0[NS_ + base] = qr * a;
}

// ---------------------------------------------------------------------------
// Conv + bias (+ BN/relu applied to INPUT on load) + BN-stat partials.
// Each block: 8 rows (p).  Thread t: row r=t>>5, e-group eg=t&31, computes
// e = eg + 32*j (j<4) for all OC channels -> strided e keeps LDS reads
// conflict-free (consecutive lanes -> consecutive addresses).
// ---------------------------------------------------------------------------
template <int IC, int OC, int KW, int PAD, bool IN_BF16, bool BN_IN, bool OUT_BF16>
__global__ __launch_bounds__(256) void k_conv(
    const void* __restrict__ inp, const float* __restrict__ wgt,
    const float* __restrict__ bias, const float* __restrict__ bnAB,
    void* __restrict__ outp, float* __restrict__ partial) {
  constexpr int PW = E_ + 2 * PAD;
  constexpr int ROWS = 8;
  constexpr int LIC = (IC == 2) ? 1 : 3;   // log2(IC); IC in {2,8}

  __shared__ __align__(16) float s_in[ROWS * IC * PW];
  __shared__ __align__(16) float s_w[IC * KW * OC];   // [i][k][o]
  __shared__ float s_bias[OC];
  __shared__ float s_red[4][2 * OC];

  const int tid = threadIdx.x;
  const int row0 = blockIdx.x * ROWS;

  for (int idx = tid; idx < ROWS * IC * PW; idx += 256) s_in[idx] = 0.f;
  for (int idx = tid; idx < IC * KW * OC; idx += 256) {
    const int o = idx % OC, ik = idx / OC;
    const int i = ik / KW, k = ik % KW;
    s_w[idx] = wgt[(o * IC + i) * KW + k];
  }
  if (tid < OC) s_bias[tid] = bias[tid];
  __syncthreads();

  for (int idx = tid; idx < ROWS * IC * E_; idx += 256) {
    const int e = idx & (E_ - 1);
    const int t2 = idx >> 7;
    const int ic = t2 & (IC - 1);
    const int rr = t2 >> LIC;
    const size_t g = (size_t)ic * NS_ + (size_t)(row0 + rr) * E_ + e;
    float v;
    if (IN_BF16) v = __bfloat162float(((const __hip_bfloat16*)inp)[g]);
    else         v = ((const float*)inp)[g];
    if (BN_IN)   v = fmaxf(0.f, fmaf(bnAB[2 * ic], v, bnAB[2 * ic + 1]));
    s_in[(rr * IC + ic) * PW + PAD + e] = v;
  }
  __syncthreads();

  const int r = tid >> 5;
  const int eg = tid & 31;
  float acc[4][OC];
  #pragma unroll
  for (int j = 0; j < 4; j++)
    #pragma unroll
    for (int o = 0; o < OC; o++) acc[j][o] = s_bias[o];

  #pragma unroll
  for (int i = 0; i < IC; i++) {
    const float* rp = &s_in[(r * IC + i) * PW + eg];
    #pragma unroll 5
    for (int k = 0; k < KW; k++) {
      const float xa = rp[k];
      const float xb = rp[k + 32];
      const float xc = rp[k + 64];
      const float xd = rp[k + 96];
      const float* wp = &s_w[(i * KW + k) * OC];
      #pragma unroll
      for (int o = 0; o < OC; o++) {
        const float wv = wp[o];
        acc[0][o] = fmaf(wv, xa, acc[0][o]);
        acc[1][o] = fmaf(wv, xb, acc[1][o]);
        acc[2][o] = fmaf(wv, xc, acc[2][o]);
        acc[3][o] = fmaf(wv, xd, acc[3][o]);
      }
    }
  }

  // write outputs (raw conv+bias; BN applied by consumer)
  const int row_g = row0 + r;
  #pragma unroll
  for (int o = 0; o < OC; o++) {
    #pragma unroll
    for (int j = 0; j < 4; j++) {
      const size_t gi = (size_t)o * NS_ + (size_t)row_g * E_ + eg + 32 * j;
      if (OUT_BF16) ((__hip_bfloat16*)outp)[gi] = __float2bfloat16(acc[j][o]);
      else          ((float*)outp)[gi] = acc[j][o];
    }
  }

  // per-block BN-stat partials (sum, sumsq per channel) -- no atomics
  const int w = tid >> 6;
  #pragma unroll
  for (int o = 0; o < OC; o++) {
    const float a0 = acc[0][o], a1 = acc[1][o], a2 = acc[2][o], a3 = acc[3][o];
    float ls  = (a0 + a1) + (a2 + a3);
    float lss = (a0 * a0 + a1 * a1) + (a2 * a2 + a3 * a3);
    ls = wave_reduce_sum(ls);
    lss = wave_reduce_sum(lss);
    if ((tid & 63) == 0) { s_red[w][o] = ls; s_red[w][OC + o] = lss; }
  }
  __syncthreads();
  if (tid < 2 * OC) {
    const float s = s_red[0][tid] + s_red[1][tid] + s_red[2][tid] + s_red[3][tid];
    partial[blockIdx.x * (2 * OC) + tid] = s;
  }
}

// ---------------------------------------------------------------------------
// Reduce per-block partials -> A = g*rsqrt(var+eps), B = beta - mu*A
// One block per channel.
// ---------------------------------------------------------------------------
__global__ __launch_bounds__(256) void k_stats(const float* __restrict__ partial,
                                               int nblk, int oc,
                                               const float* __restrict__ g,
                                               const float* __restrict__ beta,
                                               float* __restrict__ ssout) {
  const int o = blockIdx.x;
  float s = 0.f, ss = 0.f;
  for (int b = threadIdx.x; b < nblk; b += 256) {
    s  += partial[b * 2 * oc + o];
    ss += partial[b * 2 * oc + oc + o];
  }
  s = wave_reduce_sum(s);
  ss = wave_reduce_sum(ss);
  __shared__ float sm[4][2];
  if ((threadIdx.x & 63) == 0) { sm[threadIdx.x >> 6][0] = s; sm[threadIdx.x >> 6][1] = ss; }
  __syncthreads();
  if (threadIdx.x == 0) {
    s  = sm[0][0] + sm[1][0] + sm[2][0] + sm[3][0];
    ss = sm[0][1] + sm[1][1] + sm[2][1] + sm[3][1];
    const float count = (float)NS_;
    const float mu = s / count;
    const float var = fmaxf(ss / count - mu * mu, 0.f);
    const float A = g[o] * rsqrtf(var + 1e-5f);
    const float B = beta[o] - mu * A;
    ssout[2 * o] = A;
    ssout[2 * o + 1] = B;
  }
}

// ---------------------------------------------------------------------------
// Final: per pixel p, singleW = sum_e relu(A4*y4+B4); comp = singleW*mean_e(x0);
// ydb = 20*log10(|comp| + 1e-20).  One wave per pixel (lane covers e, e+64).
// Emits per-block max partials for the global max.
// ---------------------------------------------------------------------------
__global__ __launch_bounds__(256) void k_final(const float* __restrict__ x0,
                                               const float* __restrict__ y4,
                                               const float* __restrict__ ss4,
                                               float* __restrict__ ydb,
                                               float* __restrict__ pmax) {
  const int w = threadIdx.x >> 6;
  const int lane = threadIdx.x & 63;
  const int p = blockIdx.x * 4 + w;
  const float A = ss4[0], B = ss4[1];
  const size_t base = (size_t)p * E_;

  float si = x0[base + lane] + x0[base + lane + 64];
  float sq = x0[NS_ + base + lane] + x0[NS_ + base + lane + 64];
  float sw = fmaxf(0.f, fmaf(A, y4[base + lane], B)) +
             fmaxf(0.f, fmaf(A, y4[base + lane + 64], B));
  si = wave_reduce_sum(si);
  sq = wave_reduce_sum(sq);
  sw = wave_reduce_sum(sw);

  __shared__ float s_m[4];
  if (lane == 0) {
    const float ci = sw * si * (1.f / (float)E_);
    const float cq = sw * sq * (1.f / (float)E_);
    const float mag = sqrtf(ci * ci + cq * cq);
    const float v = 20.f * log10f(mag + 1e-20f);
    ydb[p] = v;
    s_m[w] = v;
  }
  __syncthreads();
  if (threadIdx.x == 0)
    pmax[blockIdx.x] = fmaxf(fmaxf(s_m[0], s_m[1]), fmaxf(s_m[2], s_m[3]));
}

__global__ __launch_bounds__(256) void k_maxred(const float* __restrict__ pmax,
                                                int n, float* __restrict__ gmax) {
  float m = -3.4e38f;
  for (int i = threadIdx.x; i < n; i += 256) m = fmaxf(m, pmax[i]);
  m = wave_reduce_max(m);
  __shared__ float sm[4];
  if ((threadIdx.x & 63) == 0) sm[threadIdx.x >> 6] = m;
  __syncthreads();
  if (threadIdx.x == 0)
    gmax[0] = fmaxf(fmaxf(sm[0], sm[1]), fmaxf(sm[2], sm[3]));
}

__global__ __launch_bounds__(256) void k_sub(const float* __restrict__ ydb,
                                             const float* __restrict__ gmax,
                                             float* __restrict__ out) {
  const int i = blockIdx.x * 256 + threadIdx.x;
  out[i] = ydb[i] - gmax[0];
}

// ---------------------------------------------------------------------------
// Workspace layout (bytes); total 168,198,408
// ---------------------------------------------------------------------------
static constexpr size_t OFF_X0   = 0;                            // 33,554,432  (2*NS f32)
static constexpr size_t OFF_A    = 33554432;                     // 67,108,864  (8*NS bf16)
static constexpr size_t OFF_B    = 100663296;                    // 67,108,864  (8*NS bf16 / y4 f32)
static constexpr size_t OFF_YDB  = 167772160;                    // 131,072
static constexpr size_t OFF_PART = 167903232;                    // 262,144 (4096 blk * 16 f32)
static constexpr size_t OFF_PMAX = 168165376;                    // 32,768
static constexpr size_t OFF_SS   = 168198144;                    // 256 (4 layers * 8 ch * {A,B})
static constexpr size_t OFF_MAXSQ= 168198400;                    // 4
static constexpr size_t OFF_GMAX = 168198404;                    // 4

extern "C" void kernel_launch(void* const* d_in, const int* in_sizes, int n_in,
                              void* d_out, int out_size, void* d_ws, size_t ws_size,
                              hipStream_t stream) {
  const float* idata     = (const float*)d_in[0];
  const float* qdata     = (const float*)d_in[1];
  const float* angles    = (const float*)d_in[2];
  const float* ele_pos   = (const float*)d_in[3];
  const float* time_zero = (const float*)d_in[4];
  const float* grid      = (const float*)d_in[5];
  const float* w1 = (const float*)d_in[6];  const float* b1 = (const float*)d_in[7];
  const float* g1 = (const float*)d_in[8];  const float* be1 = (const float*)d_in[9];
  const float* w2 = (const float*)d_in[10]; const float* b2 = (const float*)d_in[11];
  const float* g2 = (const float*)d_in[12]; const float* be2 = (const float*)d_in[13];
  const float* w3 = (const float*)d_in[14]; const float* b3 = (const float*)d_in[15];
  const float* g3 = (const float*)d_in[16]; const float* be3 = (const float*)d_in[17];
  const float* w4 = (const float*)d_in[18]; const float* b4 = (const float*)d_in[19];
  const float* g4 = (const float*)d_in[20]; const float* be4 = (const float*)d_in[21];

  char* ws = (char*)d_ws;
  float*          x0    = (float*)(ws + OFF_X0);
  __hip_bfloat16* bufA  = (__hip_bfloat16*)(ws + OFF_A);
  __hip_bfloat16* bufB  = (__hip_bfloat16*)(ws + OFF_B);
  float*          y4    = (float*)(ws + OFF_B);     // reuse (y2 dead by then)
  float*          ydb   = (float*)(ws + OFF_YDB);
  float*          part  = (float*)(ws + OFF_PART);
  float*          pmax  = (float*)(ws + OFF_PMAX);
  float*          ssAB  = (float*)(ws + OFF_SS);
  unsigned int*   maxsq = (unsigned int*)(ws + OFF_MAXSQ);
  float*          gmax  = (float*)(ws + OFF_GMAX);

  hipMemsetAsync(maxsq, 0, sizeof(unsigned int), stream);

  k_nrm<<<1024, 256, 0, stream>>>(idata, qdata, maxsq);
  k_beamform<<<NPIX / 2, 256, 0, stream>>>(idata, qdata, angles, ele_pos,
                                           time_zero, grid, maxsq, x0);

  // conv1: 2->8, K=65, pad=32; input f32 x0 (no BN); output bf16 bufA
  k_conv<2, 8, 65, 32, false, false, true><<<4096, 256, 0, stream>>>(
      x0, w1, b1, nullptr, bufA, part);
  k_stats<<<8, 256, 0, stream>>>(part, 4096, 8, g1, be1, ssAB + 0);

  // conv2: 8->8, K=15, pad=7; input bufA with BN1+relu; output bufB
  k_conv<8, 8, 15, 7, true, true, true><<<4096, 256, 0, stream>>>(
      bufA, w2, b2, ssAB + 0, bufB, part);
  k_stats<<<8, 256, 0, stream>>>(part, 4096, 8, g2, be2, ssAB + 16);

  // conv3: 8->8, K=15, pad=7; input bufB with BN2+relu; output bufA
  k_conv<8, 8, 15, 7, true, true, true><<<4096, 256, 0, stream>>>(
      bufB, w3, b3, ssAB + 16, bufA, part);
  k_stats<<<8, 256, 0, stream>>>(part, 4096, 8, g3, be3, ssAB + 32);

  // conv4: 8->1, K=3, pad=1; input bufA with BN3+relu; output f32 y4
  k_conv<8, 1, 3, 1, true, true, false><<<4096, 256, 0, stream>>>(
      bufA, w4, b4, ssAB + 32, (void*)y4, part);
  k_stats<<<1, 256, 0, stream>>>(part, 4096, 1, g4, be4, ssAB + 48);

  k_final<<<NPIX / 4, 256, 0, stream>>>(x0, y4, ssAB + 48, ydb, pmax);
  k_maxred<<<1, 256, 0, stream>>>(pmax, NPIX / 4, gmax);
  k_sub<<<NPIX / 256, 256, 0, stream>>>(ydb, gmax, (float*)d_out);
}

// Round 4
// 531.843 us; speedup vs baseline: 1.1882x; 1.1882x over previous
//
#include <hip/hip_runtime.h>
#include <hip/hip_bf16.h>

// ---------------------------------------------------------------------------
// Task1_bf_final_CSW2D round 4: MFMA convs with CORRECT pad semantics.
//
// Reference computes pad(relu(BN(x))): zero-padding applies AFTER BN+relu.
// R2/R3 bug: BN was applied to the padded buffer, turning pads into relu(B).
// Fix: conv23 zeroes halo B-fragments in-register (each uint4 = one e), and
// conv4 bounds-checks its taps.  Halo memory contents are now irrelevant.
//
// Layouts (activations channel-interleaved with e-halo):
//   x0p : bf16 pairs [p][208][2]  (slot = 32+e; halos zero)  conv1 input
//   x0c : bf16 pairs [p][128][2]  compact, for k_final
//   buf : bf16      [p][144][8]   (unit16B per e, slot = 7+e; halos unused)
// Conv as GEMM via mfma_f32_16x16x32_bf16:
//   A = weights (m = o, 8 real + 8 zero rows), B = x window (n = e-col).
//   A and B share the (quad, element)->(tap, ic) assignment, so any
//   within-MFMA k-permutation cancels.
// BN of layer L is folded into layer L+1's B-fragment unpack (A*x+B, relu).
// ---------------------------------------------------------------------------

#define E_    128
#define NPIX  32768
#define NS_   (NPIX * E_)
#define NSAMP 2048

static constexpr double PI_D     = 3.14159265358979323846;
static constexpr double FS_D     = 20832000.0;
static constexpr double FDEMOD_D = 5208000.0;
static constexpr double C_D      = 1540.0;

typedef __attribute__((ext_vector_type(8))) short short8;
typedef __attribute__((ext_vector_type(4))) float f32x4;

union U8 { uint4 u4; unsigned u32[4]; unsigned short us[8]; short8 s8; };

__device__ __forceinline__ unsigned short f2bf(float f) {
  unsigned u = __float_as_uint(f);
  unsigned r = (u + 0x7fffu + ((u >> 16) & 1u)) >> 16;
  return (unsigned short)r;
}
__device__ __forceinline__ float bflo(unsigned w) { return __uint_as_float(w << 16); }
__device__ __forceinline__ float bfhi(unsigned w) { return __uint_as_float(w & 0xFFFF0000u); }

__device__ __forceinline__ float wave_reduce_sum(float v) {
  #pragma unroll
  for (int off = 32; off; off >>= 1) v += __shfl_xor(v, off);
  return v;
}
__device__ __forceinline__ float wave_reduce_max(float v) {
  #pragma unroll
  for (int off = 32; off; off >>= 1) v = fmaxf(v, __shfl_xor(v, off));
  return v;
}

// ---------------------------------------------------------------------------
// zero x0p halos (ws is re-poisoned 0xAA before every launch) + maxsq
// ---------------------------------------------------------------------------
__global__ __launch_bounds__(256) void k_zero_x0(uint4* __restrict__ x0p,
                                                 unsigned* __restrict__ maxsq) {
  const int idx = blockIdx.x * 256 + threadIdx.x;
  const int row = idx >> 5, k = idx & 31;
  if (idx == 0) *maxsq = 0u;
  if (k >= 20) return;
  const int q = (k < 8) ? k : (40 + (k - 8));   // uint4 0..7 and 40..51
  x0p[(size_t)row * 52 + q] = make_uint4(0, 0, 0, 0);
}

// ---------------------------------------------------------------------------
// global max of i^2+q^2
// ---------------------------------------------------------------------------
__global__ __launch_bounds__(256) void k_nrm(const float* __restrict__ id,
                                             const float* __restrict__ qd,
                                             unsigned int* __restrict__ maxsq) {
  const int total = 16 * 128 * 2048;
  float m = 0.f;
  for (int idx = blockIdx.x * 256 + threadIdx.x; idx < total; idx += gridDim.x * 256) {
    float iv = id[idx], qv = qd[idx];
    m = fmaxf(m, iv * iv + qv * qv);
  }
  m = wave_reduce_max(m);
  __shared__ float sm[4];
  if ((threadIdx.x & 63) == 0) sm[threadIdx.x >> 6] = m;
  __syncthreads();
  if (threadIdx.x == 0) {
    float mm = fmaxf(fmaxf(sm[0], sm[1]), fmaxf(sm[2], sm[3]));
    atomicMax(maxsq, __float_as_uint(mm));
  }
}

// ---------------------------------------------------------------------------
// beamform -> x0p (padded, conv1 input) + x0c (compact, k_final input)
// ---------------------------------------------------------------------------
__global__ __launch_bounds__(256) void k_beamform(
    const float* __restrict__ idata, const float* __restrict__ qdata,
    const float* __restrict__ angles, const float* __restrict__ ele_pos,
    const float* __restrict__ time_zero, const float* __restrict__ grid,
    const unsigned int* __restrict__ maxsq,
    unsigned* __restrict__ x0p, unsigned* __restrict__ x0c) {
  const int e = threadIdx.x & 127;
  const int p = blockIdx.x * 2 + (threadIdx.x >> 7);

  const float inv = 1.0f / sqrtf(__uint_as_float(*maxsq));
  const float px = grid[p * 3 + 0];
  const float pz = grid[p * 3 + 2];
  const float ang = angles[0];
  const float tz  = time_zero[0];

  constexpr float SC  = (float)(FS_D / C_D);
  constexpr float TH1 = (float)(PI_D * 0.5);                        // 2pi*FDEMOD/FS
  constexpr float TH2 = (float)(2.0 * PI_D * FDEMOD_D * 2.0 / C_D); // pz coeff

  float sa, ca;
  sincosf(ang, &sa, &ca);
  const float txdel = (px * sa + pz * ca + tz * (float)C_D) * SC;

  const float ex = ele_pos[e * 3 + 0];
  const float dx = px - ex;
  const float rxdel = sqrtf(dx * dx + pz * pz) * SC;

  const float delays = txdel + rxdel;
  const float d0 = floorf(delays);
  const float frac = delays - d0;
  const int i0 = (int)d0;

  const float* isig = idata + e * NSAMP;
  const float* qsig = qdata + e * NSAMP;
  const int c0 = min(max(i0, 0), NSAMP - 1);
  const int c1 = min(max(i0 + 1, 0), NSAMP - 1);
  const bool m0 = (i0 >= 0) && (i0 < NSAMP);
  const bool m1 = (i0 + 1 >= 0) && (i0 + 1 < NSAMP);
  const float iv0 = m0 ? isig[c0] : 0.f;
  const float iv1 = m1 ? isig[c1] : 0.f;
  const float qv0 = m0 ? qsig[c0] : 0.f;
  const float qv1 = m1 ? qsig[c1] : 0.f;
  const float ifoc = (iv0 * (1.f - frac) + iv1 * frac) * inv;
  const float qfoc = (qv0 * (1.f - frac) + qv1 * frac) * inv;

  const float theta = delays * TH1 - pz * TH2;
  float st, ct;
  sincosf(theta, &st, &ct);
  const float ir = ifoc * ct - qfoc * st;
  const float qr = qfoc * ct + ifoc * st;

  const float ex0 = ele_pos[0];
  const float exl = ele_pos[127 * 3];
  const float avx = fabsf(dx);
  const bool mrx = (fabsf(pz) > avx) || (avx <= 0.001f) ||
                   ((dx >= 0.001f) && (px <= ex0)) ||
                   ((dx <= -0.001f) && (px >= exl));
  const float xproj = px - pz * tanf(ang);
  const bool mtx = (xproj >= ex0 * 1.2f) && (xproj <= exl * 1.2f);
  const float a = (mrx && mtx) ? 1.f : 0.f;

  const unsigned pk = (unsigned)f2bf(ir * a) | ((unsigned)f2bf(qr * a) << 16);
  x0p[(size_t)p * 208 + 32 + e] = pk;
  x0c[(size_t)p * 128 + e] = pk;
}

// ---------------------------------------------------------------------------
// conv1: IC=2, K=65, pad=32, OC=8.  MFMA, taps padded to 80 (5 mfma / tile).
// Fragment element (kq, j): tap = m*16 + 4*(j>>1) + kq, i = j&1.
// B loads: 4 scalar dwords per mfma at slots s, s+4, s+8, s+12 (aligned).
// Input pad is pre-BN zero -> halos (zeroed in x0p) are correct as-is.
// ---------------------------------------------------------------------------
__global__ __launch_bounds__(256) void k_conv1(
    const unsigned* __restrict__ x0p, const float* __restrict__ wgt,
    const float* __restrict__ bias, uint2* __restrict__ outp,
    float* __restrict__ partial) {
  const int tid = threadIdx.x;
  const int lane = tid & 63;
  const int wv = tid >> 6;
  const int gw = blockIdx.x * 4 + wv;         // 8192 waves
  const int n = lane & 15, kq = lane >> 4;

  // A fragments (weights): element j -> tap = m*16 + 4*(j>>1) + kq, i = j&1
  short8 af[5];
  #pragma unroll
  for (int m = 0; m < 5; ++m) {
    U8 u;
    #pragma unroll
    for (int j = 0; j < 8; ++j) {
      const int tap = m * 16 + 4 * (j >> 1) + kq;
      const int i = j & 1;
      const float w = (n < 8 && tap < 65) ? wgt[(n * 2 + i) * 65 + tap] : 0.f;
      u.us[j] = f2bf(w);
    }
    af[m] = u.s8;
  }
  float bias_r[4];
  #pragma unroll
  for (int r = 0; r < 4; ++r) {
    const int oo = kq * 4 + r;
    bias_r[r] = (oo < 8) ? bias[oo] : 0.f;
  }

  float sum[4] = {0, 0, 0, 0}, ssq[4] = {0, 0, 0, 0};

  for (int p = gw; p < NPIX; p += 8192) {
    const unsigned* row = x0p + (size_t)p * 208;
    uint2* orow = outp + ((size_t)p * 144 + 7) * 2;
    for (int t = 0; t < 8; ++t) {
      f32x4 acc = {bias_r[0], bias_r[1], bias_r[2], bias_r[3]};
      const int s0 = t * 16 + n + kq;
      #pragma unroll
      for (int m = 0; m < 5; ++m) {
        U8 b;
        const unsigned* bp = row + s0 + m * 16;
        b.u32[0] = bp[0];
        b.u32[1] = bp[4];
        b.u32[2] = bp[8];
        b.u32[3] = bp[12];
        acc = __builtin_amdgcn_mfma_f32_16x16x32_bf16(af[m], b.s8, acc, 0, 0, 0);
      }
      if (lane < 32) {
        const unsigned lo = (unsigned)f2bf(acc[0]) | ((unsigned)f2bf(acc[1]) << 16);
        const unsigned hi = (unsigned)f2bf(acc[2]) | ((unsigned)f2bf(acc[3]) << 16);
        orow[(t * 16 + n) * 2 + kq] = make_uint2(lo, hi);
        #pragma unroll
        for (int r = 0; r < 4; ++r) { const float v = acc[r]; sum[r] += v; ssq[r] += v * v; }
      }
    }
  }

  // stats: reduce within 16-lane groups (lane 0 -> o=0..3, lane 16 -> o=4..7)
  #pragma unroll
  for (int off = 1; off <= 8; off <<= 1)
    #pragma unroll
    for (int r = 0; r < 4; ++r) { sum[r] += __shfl_xor(sum[r], off); ssq[r] += __shfl_xor(ssq[r], off); }
  __shared__ float s_red[4][16];
  if (lane == 0)
    #pragma unroll
    for (int r = 0; r < 4; ++r) { s_red[wv][r] = sum[r]; s_red[wv][8 + r] = ssq[r]; }
  if (lane == 16)
    #pragma unroll
    for (int r = 0; r < 4; ++r) { s_red[wv][4 + r] = sum[r]; s_red[wv][12 + r] = ssq[r]; }
  __syncthreads();
  if (tid < 16)
    partial[blockIdx.x * 16 + tid] =
        s_red[0][tid] + s_red[1][tid] + s_red[2][tid] + s_red[3][tid];
}

// ---------------------------------------------------------------------------
// conv2/3: IC=8, K=15, pad=7, OC=8.  BN+relu of input fused in B-frag unpack;
// halo fragments (slot<7 or slot>134 i.e. e outside [0,128)) are forced to 0
// IN-REGISTER, matching the reference's pad(relu(BN(x))) semantics.
// ---------------------------------------------------------------------------
__device__ __forceinline__ short8 bn_frag(uint4 v, const float* A, const float* B) {
  U8 in; in.u4 = v;
  U8 out;
  #pragma unroll
  for (int w = 0; w < 4; ++w) {
    const unsigned wd = in.u32[w];
    const float yl = fmaxf(0.f, fmaf(A[2 * w], bflo(wd), B[2 * w]));
    const float yh = fmaxf(0.f, fmaf(A[2 * w + 1], bfhi(wd), B[2 * w + 1]));
    out.us[2 * w] = f2bf(yl);
    out.us[2 * w + 1] = f2bf(yh);
  }
  return out.s8;
}

__global__ __launch_bounds__(256) void k_conv23(
    const uint4* __restrict__ inp, const float* __restrict__ wgt,
    const float* __restrict__ bias, const float* __restrict__ bnAB,
    uint2* __restrict__ outp, float* __restrict__ partial) {
  const int tid = threadIdx.x;
  const int lane = tid & 63;
  const int wv = tid >> 6;
  const int gw = blockIdx.x * 4 + wv;
  const int n = lane & 15, kq = lane >> 4;

  float A[8], Bc[8];
  #pragma unroll
  for (int i = 0; i < 8; ++i) { A[i] = bnAB[2 * i]; Bc[i] = bnAB[2 * i + 1]; }

  // A fragments: element j -> tap = m*4 + kq, i = j
  short8 af[4];
  #pragma unroll
  for (int m = 0; m < 4; ++m) {
    U8 u;
    #pragma unroll
    for (int j = 0; j < 8; ++j) {
      const int tap = m * 4 + kq;
      const float w = (n < 8 && tap < 15) ? wgt[(n * 8 + j) * 15 + tap] : 0.f;
      u.us[j] = f2bf(w);
    }
    af[m] = u.s8;
  }
  float bias_r[4];
  #pragma unroll
  for (int r = 0; r < 4; ++r) {
    const int oo = kq * 4 + r;
    bias_r[r] = (oo < 8) ? bias[oo] : 0.f;
  }

  const short8 zfrag = short8{0, 0, 0, 0, 0, 0, 0, 0};
  float sum[4] = {0, 0, 0, 0}, ssq[4] = {0, 0, 0, 0};

  for (int p = gw; p < NPIX; p += 8192) {
    const uint4* row = inp + (size_t)p * 144;
    uint2* orow = outp + ((size_t)p * 144 + 7) * 2;
    for (int t = 0; t < 8; ++t) {
      f32x4 acc = {bias_r[0], bias_r[1], bias_r[2], bias_r[3]};
      const int base = t * 16 + n + kq;
      #pragma unroll
      for (int m = 0; m < 4; ++m) {
        const int s = base + m * 4;
        const uint4 raw = row[s];
        const bool pad = (s < 7) || (s > 134);     // e outside [0,128)
        const short8 b = pad ? zfrag : bn_frag(raw, A, Bc);
        acc = __builtin_amdgcn_mfma_f32_16x16x32_bf16(af[m], b, acc, 0, 0, 0);
      }
      if (lane < 32) {
        const unsigned lo = (unsigned)f2bf(acc[0]) | ((unsigned)f2bf(acc[1]) << 16);
        const unsigned hi = (unsigned)f2bf(acc[2]) | ((unsigned)f2bf(acc[3]) << 16);
        orow[(t * 16 + n) * 2 + kq] = make_uint2(lo, hi);
        #pragma unroll
        for (int r = 0; r < 4; ++r) { const float v = acc[r]; sum[r] += v; ssq[r] += v * v; }
      }
    }
  }

  #pragma unroll
  for (int off = 1; off <= 8; off <<= 1)
    #pragma unroll
    for (int r = 0; r < 4; ++r) { sum[r] += __shfl_xor(sum[r], off); ssq[r] += __shfl_xor(ssq[r], off); }
  __shared__ float s_red[4][16];
  if (lane == 0)
    #pragma unroll
    for (int r = 0; r < 4; ++r) { s_red[wv][r] = sum[r]; s_red[wv][8 + r] = ssq[r]; }
  if (lane == 16)
    #pragma unroll
    for (int r = 0; r < 4; ++r) { s_red[wv][4 + r] = sum[r]; s_red[wv][12 + r] = ssq[r]; }
  __syncthreads();
  if (tid < 16)
    partial[blockIdx.x * 16 + tid] =
        s_red[0][tid] + s_red[1][tid] + s_red[2][tid] + s_red[3][tid];
}

// ---------------------------------------------------------------------------
// conv4: IC=8, K=3, pad=1, OC=1.  VALU; BN3+relu fused on load; taps with
// e+kt-1 outside [0,128) contribute exactly 0 (post-BN pad).  f32 out.
// ---------------------------------------------------------------------------
__global__ __launch_bounds__(256) void k_conv4(
    const uint4* __restrict__ inp, const float* __restrict__ bnAB,
    const float* __restrict__ w4, const float* __restrict__ b4,
    float* __restrict__ y4, float* __restrict__ partial) {
  const int idx = blockIdx.x * 256 + threadIdx.x;
  const int p = idx >> 7, e = idx & 127;

  float A[8], Bc[8];
  #pragma unroll
  for (int i = 0; i < 8; ++i) { A[i] = bnAB[2 * i]; Bc[i] = bnAB[2 * i + 1]; }

  float acc = b4[0];
  const uint4* row = inp + (size_t)p * 144 + 7 + e;
  #pragma unroll
  for (int kt = 0; kt < 3; ++kt) {
    const int ee = e + kt - 1;
    if (ee >= 0 && ee < E_) {
      U8 u; u.u4 = row[kt - 1];
      #pragma unroll
      for (int i = 0; i < 8; ++i) {
        const unsigned wd = u.u32[i >> 1];
        const float x = (i & 1) ? bfhi(wd) : bflo(wd);
        const float v = fmaxf(0.f, fmaf(A[i], x, Bc[i]));
        acc = fmaf(w4[i * 3 + kt], v, acc);
      }
    }
  }
  y4[idx] = acc;

  float s = wave_reduce_sum(acc);
  float ss = wave_reduce_sum(acc * acc);
  __shared__ float sm[4][2];
  if ((threadIdx.x & 63) == 0) { sm[threadIdx.x >> 6][0] = s; sm[threadIdx.x >> 6][1] = ss; }
  __syncthreads();
  if (threadIdx.x == 0) {
    partial[blockIdx.x * 2 + 0] = sm[0][0] + sm[1][0] + sm[2][0] + sm[3][0];
    partial[blockIdx.x * 2 + 1] = sm[0][1] + sm[1][1] + sm[2][1] + sm[3][1];
  }
}

// ---------------------------------------------------------------------------
// BN stats finalize: A = g*rsqrt(var+eps), B = beta - mu*A
// ---------------------------------------------------------------------------
__global__ __launch_bounds__(256) void k_stats(const float* __restrict__ partial,
                                               int nblk, int oc,
                                               const float* __restrict__ g,
                                               const float* __restrict__ beta,
                                               float* __restrict__ ssout) {
  const int o = blockIdx.x;
  float s = 0.f, ss = 0.f;
  for (int b = threadIdx.x; b < nblk; b += 256) {
    s  += partial[b * 2 * oc + o];
    ss += partial[b * 2 * oc + oc + o];
  }
  s = wave_reduce_sum(s);
  ss = wave_reduce_sum(ss);
  __shared__ float sm[4][2];
  if ((threadIdx.x & 63) == 0) { sm[threadIdx.x >> 6][0] = s; sm[threadIdx.x >> 6][1] = ss; }
  __syncthreads();
  if (threadIdx.x == 0) {
    s  = sm[0][0] + sm[1][0] + sm[2][0] + sm[3][0];
    ss = sm[0][1] + sm[1][1] + sm[2][1] + sm[3][1];
    const float count = (float)NS_;
    const float mu = s / count;
    const float var = fmaxf(ss / count - mu * mu, 0.f);
    const float Av = g[o] * rsqrtf(var + 1e-5f);
    ssout[2 * o] = Av;
    ssout[2 * o + 1] = beta[o] - mu * Av;
  }
}

// ---------------------------------------------------------------------------
// final: singleW = sum_e relu(A4*y4+B4); comp = singleW*mean_e(x); dB
// ---------------------------------------------------------------------------
__global__ __launch_bounds__(256) void k_final(const unsigned* __restrict__ x0c,
                                               const float* __restrict__ y4,
                                               const float* __restrict__ ss4,
                                               float* __restrict__ ydb,
                                               float* __restrict__ pmax) {
  const int w = threadIdx.x >> 6;
  const int lane = threadIdx.x & 63;
  const int p = blockIdx.x * 4 + w;
  const float A = ss4[0], B = ss4[1];
  const size_t base = (size_t)p * E_;

  const unsigned v0 = x0c[base + lane];
  const unsigned v1 = x0c[base + lane + 64];
  float si = bflo(v0) + bflo(v1);
  float sq = bfhi(v0) + bfhi(v1);
  float sw = fmaxf(0.f, fmaf(A, y4[base + lane], B)) +
             fmaxf(0.f, fmaf(A, y4[base + lane + 64], B));
  si = wave_reduce_sum(si);
  sq = wave_reduce_sum(sq);
  sw = wave_reduce_sum(sw);

  __shared__ float s_m[4];
  if (lane == 0) {
    const float ci = sw * si * (1.f / (float)E_);
    const float cq = sw * sq * (1.f / (float)E_);
    const float mag = sqrtf(ci * ci + cq * cq);
    const float v = 20.f * log10f(mag + 1e-20f);
    ydb[p] = v;
    s_m[w] = v;
  }
  __syncthreads();
  if (threadIdx.x == 0)
    pmax[blockIdx.x] = fmaxf(fmaxf(s_m[0], s_m[1]), fmaxf(s_m[2], s_m[3]));
}

__global__ __launch_bounds__(256) void k_maxred(const float* __restrict__ pmax,
                                                int n, float* __restrict__ gmax) {
  float m = -3.4e38f;
  for (int i = threadIdx.x; i < n; i += 256) m = fmaxf(m, pmax[i]);
  m = wave_reduce_max(m);
  __shared__ float sm[4];
  if ((threadIdx.x & 63) == 0) sm[threadIdx.x >> 6] = m;
  __syncthreads();
  if (threadIdx.x == 0)
    gmax[0] = fmaxf(fmaxf(sm[0], sm[1]), fmaxf(sm[2], sm[3]));
}

__global__ __launch_bounds__(256) void k_sub(const float* __restrict__ ydb,
                                             const float* __restrict__ gmax,
                                             float* __restrict__ out) {
  const int i = blockIdx.x * 256 + threadIdx.x;
  out[i] = ydb[i] - gmax[0];
}

// ---------------------------------------------------------------------------
// Workspace layout (bytes).  Region A is time-multiplexed:
//   x0p (conv1 input, dead after conv1) -> buf2 (conv2 out, dead after conv3)
//   -> y4 + ydb + pmax (finals).
// ---------------------------------------------------------------------------
static constexpr size_t OFF_A     = 0;           // 75,497,472 region
static constexpr size_t OFF_Y4    = 0;           // f32 [NS]          (in A)
static constexpr size_t OFF_YDB   = 16777216;    // f32 [NPIX]        (in A)
static constexpr size_t OFF_PMAX  = 16908288;    // f32 [8192]        (in A)
static constexpr size_t OFF_BUF1  = 75497472;    // 75,497,472
static constexpr size_t OFF_X0C   = 150994944;   // 16,777,216
static constexpr size_t OFF_PART  = 167772160;   // 262,144
static constexpr size_t OFF_SS    = 168034304;   // 256
static constexpr size_t OFF_MAXSQ = 168034560;   // 4
static constexpr size_t OFF_GMAX  = 168034564;   // 4

extern "C" void kernel_launch(void* const* d_in, const int* in_sizes, int n_in,
                              void* d_out, int out_size, void* d_ws, size_t ws_size,
                              hipStream_t stream) {
  const float* idata     = (const float*)d_in[0];
  const float* qdata     = (const float*)d_in[1];
  const float* angles    = (const float*)d_in[2];
  const float* ele_pos   = (const float*)d_in[3];
  const float* time_zero = (const float*)d_in[4];
  const float* grid      = (const float*)d_in[5];
  const float* w1 = (const float*)d_in[6];  const float* b1 = (const float*)d_in[7];
  const float* g1 = (const float*)d_in[8];  const float* be1 = (const float*)d_in[9];
  const float* w2 = (const float*)d_in[10]; const float* b2 = (const float*)d_in[11];
  const float* g2 = (const float*)d_in[12]; const float* be2 = (const float*)d_in[13];
  const float* w3 = (const float*)d_in[14]; const float* b3 = (const float*)d_in[15];
  const float* g3 = (const float*)d_in[16]; const float* be3 = (const float*)d_in[17];
  const float* w4 = (const float*)d_in[18]; const float* b4 = (const float*)d_in[19];
  const float* g4 = (const float*)d_in[20]; const float* be4 = (const float*)d_in[21];

  char* ws = (char*)d_ws;
  unsigned*     x0p   = (unsigned*)(ws + OFF_A);       // [p][208] bf16-pairs
  uint4*        buf2  = (uint4*)(ws + OFF_A);          // [p][144] units
  float*        y4    = (float*)(ws + OFF_Y4);
  float*        ydb   = (float*)(ws + OFF_YDB);
  float*        pmax  = (float*)(ws + OFF_PMAX);
  uint4*        buf1  = (uint4*)(ws + OFF_BUF1);
  unsigned*     x0c   = (unsigned*)(ws + OFF_X0C);
  float*        part  = (float*)(ws + OFF_PART);
  float*        ssAB  = (float*)(ws + OFF_SS);
  unsigned int* maxsq = (unsigned int*)(ws + OFF_MAXSQ);
  float*        gmax  = (float*)(ws + OFF_GMAX);

  // init zeros (x0p halos + maxsq); buf halos never consumed -> no zeroing
  k_zero_x0<<<4096, 256, 0, stream>>>((uint4*)x0p, maxsq);

  k_nrm<<<1024, 256, 0, stream>>>(idata, qdata, maxsq);
  k_beamform<<<NPIX / 2, 256, 0, stream>>>(idata, qdata, angles, ele_pos,
                                           time_zero, grid, maxsq, x0p, x0c);

  // conv1: x0p -> buf1 (raw conv+bias)
  k_conv1<<<2048, 256, 0, stream>>>(x0p, w1, b1, (uint2*)buf1, part);
  k_stats<<<8, 256, 0, stream>>>(part, 2048, 8, g1, be1, ssAB + 0);

  // conv2: buf1 -> buf2 (overlays dead x0p)
  k_conv23<<<2048, 256, 0, stream>>>(buf1, w2, b2, ssAB + 0, (uint2*)buf2, part);
  k_stats<<<8, 256, 0, stream>>>(part, 2048, 8, g2, be2, ssAB + 16);

  // conv3: buf2 -> buf1
  k_conv23<<<2048, 256, 0, stream>>>(buf2, w3, b3, ssAB + 16, (uint2*)buf1, part);
  k_stats<<<8, 256, 0, stream>>>(part, 2048, 8, g3, be3, ssAB + 32);

  // conv4: buf1 -> y4 (overlays dead buf2)
  k_conv4<<<NS_ / 256, 256, 0, stream>>>(buf1, ssAB + 32, w4, b4, y4, part);
  k_stats<<<1, 256, 0, stream>>>(part, NS_ / 256, 1, g4, be4, ssAB + 48);

  k_final<<<NPIX / 4, 256, 0, stream>>>(x0c, y4, ssAB + 48, ydb, pmax);
  k_maxred<<<1, 256, 0, stream>>>(pmax, NPIX / 4, gmax);
  k_sub<<<NPIX / 256, 256, 0, stream>>>(ydb, gmax, (float*)d_out);
}

// Round 5
// 351.462 us; speedup vs baseline: 1.7980x; 1.5132x over previous
//
#include <hip/hip_runtime.h>
#include <hip/hip_bf16.h>

// ---------------------------------------------------------------------------
// Task1_bf_final_CSW2D round 5: conv2/3 LDS-staged (BN applied once per
// element per wave, fragments via 16B-aligned ds_read_b128).
//
// R4 counters: conv23 VALUBusy=84%, MfmaUtil=5% -> BN unpack done ~8x
// redundantly per element in the fragment path.  Now: each wave stages its
// row into private LDS (144 slots, halos zeroed -> pad(relu(BN(x)))
// semantics preserved), BN+relu+repack once per element, fragments are
// ds_read_b128 at slot*16 (always aligned).
//
// Layouts:
//   x0p : bf16 pairs [p][208][2]  (slot = 32+e; halos zero)  conv1 input
//   x0c : bf16 pairs [p][128][2]  compact, for k_final
//   buf : bf16      [p][128][8]   COMPACT 16B per e (no global halos)
// Conv as GEMM via mfma_f32_16x16x32_bf16:
//   A = weights (m = o, 8 real + 8 zero rows), B = x window (n = e-col).
//   A and B share the (quad, element)->(tap, ic) assignment, so any
//   within-MFMA k-permutation cancels.
// ---------------------------------------------------------------------------

#define E_    128
#define NPIX  32768
#define NS_   (NPIX * E_)
#define NSAMP 2048

static constexpr double PI_D     = 3.14159265358979323846;
static constexpr double FS_D     = 20832000.0;
static constexpr double FDEMOD_D = 5208000.0;
static constexpr double C_D      = 1540.0;

typedef __attribute__((ext_vector_type(8))) short short8;
typedef __attribute__((ext_vector_type(4))) float f32x4;

union U8 { uint4 u4; unsigned u32[4]; unsigned short us[8]; short8 s8; };

__device__ __forceinline__ unsigned short f2bf(float f) {
  unsigned u = __float_as_uint(f);
  unsigned r = (u + 0x7fffu + ((u >> 16) & 1u)) >> 16;
  return (unsigned short)r;
}
__device__ __forceinline__ float bflo(unsigned w) { return __uint_as_float(w << 16); }
__device__ __forceinline__ float bfhi(unsigned w) { return __uint_as_float(w & 0xFFFF0000u); }

__device__ __forceinline__ float wave_reduce_sum(float v) {
  #pragma unroll
  for (int off = 32; off; off >>= 1) v += __shfl_xor(v, off);
  return v;
}
__device__ __forceinline__ float wave_reduce_max(float v) {
  #pragma unroll
  for (int off = 32; off; off >>= 1) v = fmaxf(v, __shfl_xor(v, off));
  return v;
}

// BN+relu one 16B unit (8 channels of one e), repack to bf16
__device__ __forceinline__ uint4 bn_unit(uint4 v, const float* A, const float* B) {
  U8 in; in.u4 = v;
  U8 out;
  #pragma unroll
  for (int w = 0; w < 4; ++w) {
    const unsigned wd = in.u32[w];
    const float yl = fmaxf(0.f, fmaf(A[2 * w], bflo(wd), B[2 * w]));
    const float yh = fmaxf(0.f, fmaf(A[2 * w + 1], bfhi(wd), B[2 * w + 1]));
    out.us[2 * w] = f2bf(yl);
    out.us[2 * w + 1] = f2bf(yh);
  }
  return out.u4;
}

// ---------------------------------------------------------------------------
// zero x0p halos (ws is re-poisoned 0xAA before every launch) + maxsq
// ---------------------------------------------------------------------------
__global__ __launch_bounds__(256) void k_zero_x0(uint4* __restrict__ x0p,
                                                 unsigned* __restrict__ maxsq) {
  const int idx = blockIdx.x * 256 + threadIdx.x;
  const int row = idx >> 5, k = idx & 31;
  if (idx == 0) *maxsq = 0u;
  if (k >= 20) return;
  const int q = (k < 8) ? k : (40 + (k - 8));   // uint4 0..7 and 40..51
  x0p[(size_t)row * 52 + q] = make_uint4(0, 0, 0, 0);
}

// ---------------------------------------------------------------------------
// global max of i^2+q^2
// ---------------------------------------------------------------------------
__global__ __launch_bounds__(256) void k_nrm(const float* __restrict__ id,
                                             const float* __restrict__ qd,
                                             unsigned int* __restrict__ maxsq) {
  const int total = 16 * 128 * 2048;
  float m = 0.f;
  for (int idx = blockIdx.x * 256 + threadIdx.x; idx < total; idx += gridDim.x * 256) {
    float iv = id[idx], qv = qd[idx];
    m = fmaxf(m, iv * iv + qv * qv);
  }
  m = wave_reduce_max(m);
  __shared__ float sm[4];
  if ((threadIdx.x & 63) == 0) sm[threadIdx.x >> 6] = m;
  __syncthreads();
  if (threadIdx.x == 0) {
    float mm = fmaxf(fmaxf(sm[0], sm[1]), fmaxf(sm[2], sm[3]));
    atomicMax(maxsq, __float_as_uint(mm));
  }
}

// ---------------------------------------------------------------------------
// beamform -> x0p (padded, conv1 input) + x0c (compact, k_final input)
// ---------------------------------------------------------------------------
__global__ __launch_bounds__(256) void k_beamform(
    const float* __restrict__ idata, const float* __restrict__ qdata,
    const float* __restrict__ angles, const float* __restrict__ ele_pos,
    const float* __restrict__ time_zero, const float* __restrict__ grid,
    const unsigned int* __restrict__ maxsq,
    unsigned* __restrict__ x0p, unsigned* __restrict__ x0c) {
  const int e = threadIdx.x & 127;
  const int p = blockIdx.x * 2 + (threadIdx.x >> 7);

  const float inv = 1.0f / sqrtf(__uint_as_float(*maxsq));
  const float px = grid[p * 3 + 0];
  const float pz = grid[p * 3 + 2];
  const float ang = angles[0];
  const float tz  = time_zero[0];

  constexpr float SC  = (float)(FS_D / C_D);
  constexpr float TH1 = (float)(PI_D * 0.5);                        // 2pi*FDEMOD/FS
  constexpr float TH2 = (float)(2.0 * PI_D * FDEMOD_D * 2.0 / C_D); // pz coeff

  float sa, ca;
  sincosf(ang, &sa, &ca);
  const float txdel = (px * sa + pz * ca + tz * (float)C_D) * SC;

  const float ex = ele_pos[e * 3 + 0];
  const float dx = px - ex;
  const float rxdel = sqrtf(dx * dx + pz * pz) * SC;

  const float delays = txdel + rxdel;
  const float d0 = floorf(delays);
  const float frac = delays - d0;
  const int i0 = (int)d0;

  const float* isig = idata + e * NSAMP;
  const float* qsig = qdata + e * NSAMP;
  const int c0 = min(max(i0, 0), NSAMP - 1);
  const int c1 = min(max(i0 + 1, 0), NSAMP - 1);
  const bool m0 = (i0 >= 0) && (i0 < NSAMP);
  const bool m1 = (i0 + 1 >= 0) && (i0 + 1 < NSAMP);
  const float iv0 = m0 ? isig[c0] : 0.f;
  const float iv1 = m1 ? isig[c1] : 0.f;
  const float qv0 = m0 ? qsig[c0] : 0.f;
  const float qv1 = m1 ? qsig[c1] : 0.f;
  const float ifoc = (iv0 * (1.f - frac) + iv1 * frac) * inv;
  const float qfoc = (qv0 * (1.f - frac) + qv1 * frac) * inv;

  const float theta = delays * TH1 - pz * TH2;
  float st, ct;
  sincosf(theta, &st, &ct);
  const float ir = ifoc * ct - qfoc * st;
  const float qr = qfoc * ct + ifoc * st;

  const float ex0 = ele_pos[0];
  const float exl = ele_pos[127 * 3];
  const float avx = fabsf(dx);
  const bool mrx = (fabsf(pz) > avx) || (avx <= 0.001f) ||
                   ((dx >= 0.001f) && (px <= ex0)) ||
                   ((dx <= -0.001f) && (px >= exl));
  const float xproj = px - pz * tanf(ang);
  const bool mtx = (xproj >= ex0 * 1.2f) && (xproj <= exl * 1.2f);
  const float a = (mrx && mtx) ? 1.f : 0.f;

  const unsigned pk = (unsigned)f2bf(ir * a) | ((unsigned)f2bf(qr * a) << 16);
  x0p[(size_t)p * 208 + 32 + e] = pk;
  x0c[(size_t)p * 128 + e] = pk;
}

// ---------------------------------------------------------------------------
// conv1: IC=2, K=65, pad=32, OC=8.  MFMA, taps padded to 80 (5 mfma / tile).
// Fragment element (kq, j): tap = m*16 + 4*(j>>1) + kq, i = j&1.
// B loads: 4 scalar dwords per mfma at slots s, s+4, s+8, s+12 (aligned).
// Input pad is pre-BN zero -> halos (zeroed in x0p) are correct as-is.
// Output: compact [p][128][8ch] (16B per e).
// ---------------------------------------------------------------------------
__global__ __launch_bounds__(256) void k_conv1(
    const unsigned* __restrict__ x0p, const float* __restrict__ wgt,
    const float* __restrict__ bias, uint2* __restrict__ outp,
    float* __restrict__ partial) {
  const int tid = threadIdx.x;
  const int lane = tid & 63;
  const int wv = tid >> 6;
  const int gw = blockIdx.x * 4 + wv;         // 8192 waves
  const int n = lane & 15, kq = lane >> 4;

  // A fragments (weights): element j -> tap = m*16 + 4*(j>>1) + kq, i = j&1
  short8 af[5];
  #pragma unroll
  for (int m = 0; m < 5; ++m) {
    U8 u;
    #pragma unroll
    for (int j = 0; j < 8; ++j) {
      const int tap = m * 16 + 4 * (j >> 1) + kq;
      const int i = j & 1;
      const float w = (n < 8 && tap < 65) ? wgt[(n * 2 + i) * 65 + tap] : 0.f;
      u.us[j] = f2bf(w);
    }
    af[m] = u.s8;
  }
  float bias_r[4];
  #pragma unroll
  for (int r = 0; r < 4; ++r) {
    const int oo = kq * 4 + r;
    bias_r[r] = (oo < 8) ? bias[oo] : 0.f;
  }

  float sum[4] = {0, 0, 0, 0}, ssq[4] = {0, 0, 0, 0};

  for (int p = gw; p < NPIX; p += 8192) {
    const unsigned* row = x0p + (size_t)p * 208;
    uint2* orow = outp + (size_t)p * 256;
    for (int t = 0; t < 8; ++t) {
      f32x4 acc = {bias_r[0], bias_r[1], bias_r[2], bias_r[3]};
      const int s0 = t * 16 + n + kq;
      #pragma unroll
      for (int m = 0; m < 5; ++m) {
        U8 b;
        const unsigned* bp = row + s0 + m * 16;
        b.u32[0] = bp[0];
        b.u32[1] = bp[4];
        b.u32[2] = bp[8];
        b.u32[3] = bp[12];
        acc = __builtin_amdgcn_mfma_f32_16x16x32_bf16(af[m], b.s8, acc, 0, 0, 0);
      }
      if (lane < 32) {
        const unsigned lo = (unsigned)f2bf(acc[0]) | ((unsigned)f2bf(acc[1]) << 16);
        const unsigned hi = (unsigned)f2bf(acc[2]) | ((unsigned)f2bf(acc[3]) << 16);
        orow[(t * 16 + n) * 2 + kq] = make_uint2(lo, hi);
        #pragma unroll
        for (int r = 0; r < 4; ++r) { const float v = acc[r]; sum[r] += v; ssq[r] += v * v; }
      }
    }
  }

  // stats: reduce within 16-lane groups (lane 0 -> o=0..3, lane 16 -> o=4..7)
  #pragma unroll
  for (int off = 1; off <= 8; off <<= 1)
    #pragma unroll
    for (int r = 0; r < 4; ++r) { sum[r] += __shfl_xor(sum[r], off); ssq[r] += __shfl_xor(ssq[r], off); }
  __shared__ float s_red[4][16];
  if (lane == 0)
    #pragma unroll
    for (int r = 0; r < 4; ++r) { s_red[wv][r] = sum[r]; s_red[wv][8 + r] = ssq[r]; }
  if (lane == 16)
    #pragma unroll
    for (int r = 0; r < 4; ++r) { s_red[wv][4 + r] = sum[r]; s_red[wv][12 + r] = ssq[r]; }
  __syncthreads();
  if (tid < 16)
    partial[blockIdx.x * 16 + tid] =
        s_red[0][tid] + s_red[1][tid] + s_red[2][tid] + s_red[3][tid];
}

// ---------------------------------------------------------------------------
// conv2/3: IC=8, K=15, pad=7, OC=8.  Per-wave LDS row staging:
//   stage = load compact row (128 uint4), BN+relu+repack ONCE per element,
//   store to private LDS slots 7..134; slots 0..6 & 135..143 zeroed (pad
//   AFTER BN+relu, matching reference).  Fragments: ds_read_b128 at
//   slot = t*16 + n + kq + m*4 (byte = slot*16, always aligned).
// A mapping: tap = m*4 + kq, ic = j (same permutation as B -> cancels).
// ---------------------------------------------------------------------------
__global__ __launch_bounds__(256) void k_conv23(
    const uint4* __restrict__ inp, const float* __restrict__ wgt,
    const float* __restrict__ bias, const float* __restrict__ bnAB,
    uint2* __restrict__ outp, float* __restrict__ partial) {
  __shared__ uint4 s_row[4][144];
  const int tid = threadIdx.x;
  const int lane = tid & 63;
  const int wv = tid >> 6;
  const int gw = blockIdx.x * 4 + wv;
  const int n = lane & 15, kq = lane >> 4;

  float A[8], Bc[8];
  #pragma unroll
  for (int i = 0; i < 8; ++i) { A[i] = bnAB[2 * i]; Bc[i] = bnAB[2 * i + 1]; }

  // A fragments: element j -> tap = m*4 + kq, i = j
  short8 af[4];
  #pragma unroll
  for (int m = 0; m < 4; ++m) {
    U8 u;
    #pragma unroll
    for (int j = 0; j < 8; ++j) {
      const int tap = m * 4 + kq;
      const float w = (n < 8 && tap < 15) ? wgt[(n * 8 + j) * 15 + tap] : 0.f;
      u.us[j] = f2bf(w);
    }
    af[m] = u.s8;
  }
  float bias_r[4];
  #pragma unroll
  for (int r = 0; r < 4; ++r) {
    const int oo = kq * 4 + r;
    bias_r[r] = (oo < 8) ? bias[oo] : 0.f;
  }

  uint4* lds = s_row[wv];
  // zero halo slots once (post-BN pad semantics): 0..6 and 135..143
  if (lane < 7)  lds[lane] = make_uint4(0, 0, 0, 0);
  if (lane >= 7 && lane < 16) lds[128 + lane] = make_uint4(0, 0, 0, 0);

  float sum[4] = {0, 0, 0, 0}, ssq[4] = {0, 0, 0, 0};

  for (int p = gw; p < NPIX; p += 8192) {
    const uint4* grow = inp + (size_t)p * 128;
    const uint4 v0 = grow[lane];
    const uint4 v1 = grow[64 + lane];
    lds[7 + lane]  = bn_unit(v0, A, Bc);
    lds[71 + lane] = bn_unit(v1, A, Bc);
    __syncthreads();

    uint2* orow = outp + (size_t)p * 256;
    for (int t = 0; t < 8; ++t) {
      f32x4 acc = {bias_r[0], bias_r[1], bias_r[2], bias_r[3]};
      const int base = t * 16 + n + kq;
      #pragma unroll
      for (int m = 0; m < 4; ++m) {
        U8 b;
        b.u4 = lds[base + m * 4];
        acc = __builtin_amdgcn_mfma_f32_16x16x32_bf16(af[m], b.s8, acc, 0, 0, 0);
      }
      if (lane < 32) {
        const unsigned lo = (unsigned)f2bf(acc[0]) | ((unsigned)f2bf(acc[1]) << 16);
        const unsigned hi = (unsigned)f2bf(acc[2]) | ((unsigned)f2bf(acc[3]) << 16);
        orow[(t * 16 + n) * 2 + kq] = make_uint2(lo, hi);
        #pragma unroll
        for (int r = 0; r < 4; ++r) { const float v = acc[r]; sum[r] += v; ssq[r] += v * v; }
      }
    }
    __syncthreads();
  }

  #pragma unroll
  for (int off = 1; off <= 8; off <<= 1)
    #pragma unroll
    for (int r = 0; r < 4; ++r) { sum[r] += __shfl_xor(sum[r], off); ssq[r] += __shfl_xor(ssq[r], off); }
  __shared__ float s_red[4][16];
  if (lane == 0)
    #pragma unroll
    for (int r = 0; r < 4; ++r) { s_red[wv][r] = sum[r]; s_red[wv][8 + r] = ssq[r]; }
  if (lane == 16)
    #pragma unroll
    for (int r = 0; r < 4; ++r) { s_red[wv][4 + r] = sum[r]; s_red[wv][12 + r] = ssq[r]; }
  __syncthreads();
  if (tid < 16)
    partial[blockIdx.x * 16 + tid] =
        s_red[0][tid] + s_red[1][tid] + s_red[2][tid] + s_red[3][tid];
}

// ---------------------------------------------------------------------------
// conv4: IC=8, K=3, pad=1, OC=1.  VALU; BN3+relu fused on load; taps with
// e+kt-1 outside [0,128) contribute exactly 0 (post-BN pad).  f32 out.
// Input: compact [p][128][8ch].
// ---------------------------------------------------------------------------
__global__ __launch_bounds__(256) void k_conv4(
    const uint4* __restrict__ inp, const float* __restrict__ bnAB,
    const float* __restrict__ w4, const float* __restrict__ b4,
    float* __restrict__ y4, float* __restrict__ partial) {
  const int idx = blockIdx.x * 256 + threadIdx.x;
  const int p = idx >> 7, e = idx & 127;

  float A[8], Bc[8];
  #pragma unroll
  for (int i = 0; i < 8; ++i) { A[i] = bnAB[2 * i]; Bc[i] = bnAB[2 * i + 1]; }

  float acc = b4[0];
  const uint4* row = inp + (size_t)p * 128 + e;
  #pragma unroll
  for (int kt = 0; kt < 3; ++kt) {
    const int ee = e + kt - 1;
    if (ee >= 0 && ee < E_) {
      U8 u; u.u4 = row[kt - 1];
      #pragma unroll
      for (int i = 0; i < 8; ++i) {
        const unsigned wd = u.u32[i >> 1];
        const float x = (i & 1) ? bfhi(wd) : bflo(wd);
        const float v = fmaxf(0.f, fmaf(A[i], x, Bc[i]));
        acc = fmaf(w4[i * 3 + kt], v, acc);
      }
    }
  }
  y4[idx] = acc;

  float s = wave_reduce_sum(acc);
  float ss = wave_reduce_sum(acc * acc);
  __shared__ float sm[4][2];
  if ((threadIdx.x & 63) == 0) { sm[threadIdx.x >> 6][0] = s; sm[threadIdx.x >> 6][1] = ss; }
  __syncthreads();
  if (threadIdx.x == 0) {
    partial[blockIdx.x * 2 + 0] = sm[0][0] + sm[1][0] + sm[2][0] + sm[3][0];
    partial[blockIdx.x * 2 + 1] = sm[0][1] + sm[1][1] + sm[2][1] + sm[3][1];
  }
}

// ---------------------------------------------------------------------------
// BN stats finalize: A = g*rsqrt(var+eps), B = beta - mu*A
// ---------------------------------------------------------------------------
__global__ __launch_bounds__(256) void k_stats(const float* __restrict__ partial,
                                               int nblk, int oc,
                                               const float* __restrict__ g,
                                               const float* __restrict__ beta,
                                               float* __restrict__ ssout) {
  const int o = blockIdx.x;
  float s = 0.f, ss = 0.f;
  for (int b = threadIdx.x; b < nblk; b += 256) {
    s  += partial[b * 2 * oc + o];
    ss += partial[b * 2 * oc + oc + o];
  }
  s = wave_reduce_sum(s);
  ss = wave_reduce_sum(ss);
  __shared__ float sm[4][2];
  if ((threadIdx.x & 63) == 0) { sm[threadIdx.x >> 6][0] = s; sm[threadIdx.x >> 6][1] = ss; }
  __syncthreads();
  if (threadIdx.x == 0) {
    s  = sm[0][0] + sm[1][0] + sm[2][0] + sm[3][0];
    ss = sm[0][1] + sm[1][1] + sm[2][1] + sm[3][1];
    const float count = (float)NS_;
    const float mu = s / count;
    const float var = fmaxf(ss / count - mu * mu, 0.f);
    const float Av = g[o] * rsqrtf(var + 1e-5f);
    ssout[2 * o] = Av;
    ssout[2 * o + 1] = beta[o] - mu * Av;
  }
}

// ---------------------------------------------------------------------------
// final: singleW = sum_e relu(A4*y4+B4); comp = singleW*mean_e(x); dB
// ---------------------------------------------------------------------------
__global__ __launch_bounds__(256) void k_final(const unsigned* __restrict__ x0c,
                                               const float* __restrict__ y4,
                                               const float* __restrict__ ss4,
                                               float* __restrict__ ydb,
                                               float* __restrict__ pmax) {
  const int w = threadIdx.x >> 6;
  const int lane = threadIdx.x & 63;
  const int p = blockIdx.x * 4 + w;
  const float A = ss4[0], B = ss4[1];
  const size_t base = (size_t)p * E_;

  const unsigned v0 = x0c[base + lane];
  const unsigned v1 = x0c[base + lane + 64];
  float si = bflo(v0) + bflo(v1);
  float sq = bfhi(v0) + bfhi(v1);
  float sw = fmaxf(0.f, fmaf(A, y4[base + lane], B)) +
             fmaxf(0.f, fmaf(A, y4[base + lane + 64], B));
  si = wave_reduce_sum(si);
  sq = wave_reduce_sum(sq);
  sw = wave_reduce_sum(sw);

  __shared__ float s_m[4];
  if (lane == 0) {
    const float ci = sw * si * (1.f / (float)E_);
    const float cq = sw * sq * (1.f / (float)E_);
    const float mag = sqrtf(ci * ci + cq * cq);
    const float v = 20.f * log10f(mag + 1e-20f);
    ydb[p] = v;
    s_m[w] = v;
  }
  __syncthreads();
  if (threadIdx.x == 0)
    pmax[blockIdx.x] = fmaxf(fmaxf(s_m[0], s_m[1]), fmaxf(s_m[2], s_m[3]));
}

__global__ __launch_bounds__(256) void k_maxred(const float* __restrict__ pmax,
                                                int n, float* __restrict__ gmax) {
  float m = -3.4e38f;
  for (int i = threadIdx.x; i < n; i += 256) m = fmaxf(m, pmax[i]);
  m = wave_reduce_max(m);
  __shared__ float sm[4];
  if ((threadIdx.x & 63) == 0) sm[threadIdx.x >> 6] = m;
  __syncthreads();
  if (threadIdx.x == 0)
    gmax[0] = fmaxf(fmaxf(sm[0], sm[1]), fmaxf(sm[2], sm[3]));
}

__global__ __launch_bounds__(256) void k_sub(const float* __restrict__ ydb,
                                             const float* __restrict__ gmax,
                                             float* __restrict__ out) {
  const int i = blockIdx.x * 256 + threadIdx.x;
  out[i] = ydb[i] - gmax[0];
}

// ---------------------------------------------------------------------------
// Workspace layout (bytes).  Region A is time-multiplexed:
//   x0p (27MB, conv1 input, dead after conv1) -> buf2 (67MB, conv2 out,
//   dead after conv3) -> y4 + ydb + pmax (finals).
// ---------------------------------------------------------------------------
static constexpr size_t OFF_A     = 0;           // 67,108,864 region
static constexpr size_t OFF_Y4    = 0;           // f32 [NS]          (in A)
static constexpr size_t OFF_YDB   = 16777216;    // f32 [NPIX]        (in A)
static constexpr size_t OFF_PMAX  = 16908288;    // f32 [8192]        (in A)
static constexpr size_t OFF_BUF1  = 67108864;    // 67,108,864
static constexpr size_t OFF_X0C   = 134217728;   // 16,777,216
static constexpr size_t OFF_PART  = 150994944;   // 262,144
static constexpr size_t OFF_SS    = 151257088;   // 256
static constexpr size_t OFF_MAXSQ = 151257344;   // 4
static constexpr size_t OFF_GMAX  = 151257348;   // 4

extern "C" void kernel_launch(void* const* d_in, const int* in_sizes, int n_in,
                              void* d_out, int out_size, void* d_ws, size_t ws_size,
                              hipStream_t stream) {
  const float* idata     = (const float*)d_in[0];
  const float* qdata     = (const float*)d_in[1];
  const float* angles    = (const float*)d_in[2];
  const float* ele_pos   = (const float*)d_in[3];
  const float* time_zero = (const float*)d_in[4];
  const float* grid      = (const float*)d_in[5];
  const float* w1 = (const float*)d_in[6];  const float* b1 = (const float*)d_in[7];
  const float* g1 = (const float*)d_in[8];  const float* be1 = (const float*)d_in[9];
  const float* w2 = (const float*)d_in[10]; const float* b2 = (const float*)d_in[11];
  const float* g2 = (const float*)d_in[12]; const float* be2 = (const float*)d_in[13];
  const float* w3 = (const float*)d_in[14]; const float* b3 = (const float*)d_in[15];
  const float* g3 = (const float*)d_in[16]; const float* be3 = (const float*)d_in[17];
  const float* w4 = (const float*)d_in[18]; const float* b4 = (const float*)d_in[19];
  const float* g4 = (const float*)d_in[20]; const float* be4 = (const float*)d_in[21];

  char* ws = (char*)d_ws;
  unsigned*     x0p   = (unsigned*)(ws + OFF_A);       // [p][208] bf16-pairs
  uint4*        buf2  = (uint4*)(ws + OFF_A);          // [p][128] units
  float*        y4    = (float*)(ws + OFF_Y4);
  float*        ydb   = (float*)(ws + OFF_YDB);
  float*        pmax  = (float*)(ws + OFF_PMAX);
  uint4*        buf1  = (uint4*)(ws + OFF_BUF1);
  unsigned*     x0c   = (unsigned*)(ws + OFF_X0C);
  float*        part  = (float*)(ws + OFF_PART);
  float*        ssAB  = (float*)(ws + OFF_SS);
  unsigned int* maxsq = (unsigned int*)(ws + OFF_MAXSQ);
  float*        gmax  = (float*)(ws + OFF_GMAX);

  // init zeros (x0p halos + maxsq)
  k_zero_x0<<<4096, 256, 0, stream>>>((uint4*)x0p, maxsq);

  k_nrm<<<1024, 256, 0, stream>>>(idata, qdata, maxsq);
  k_beamform<<<NPIX / 2, 256, 0, stream>>>(idata, qdata, angles, ele_pos,
                                           time_zero, grid, maxsq, x0p, x0c);

  // conv1: x0p -> buf1 (raw conv+bias)
  k_conv1<<<2048, 256, 0, stream>>>(x0p, w1, b1, (uint2*)buf1, part);
  k_stats<<<8, 256, 0, stream>>>(part, 2048, 8, g1, be1, ssAB + 0);

  // conv2: buf1 -> buf2 (overlays dead x0p)
  k_conv23<<<2048, 256, 0, stream>>>(buf1, w2, b2, ssAB + 0, (uint2*)buf2, part);
  k_stats<<<8, 256, 0, stream>>>(part, 2048, 8, g2, be2, ssAB + 16);

  // conv3: buf2 -> buf1
  k_conv23<<<2048, 256, 0, stream>>>(buf2, w3, b3, ssAB + 16, (uint2*)buf1, part);
  k_stats<<<8, 256, 0, stream>>>(part, 2048, 8, g3, be3, ssAB + 32);

  // conv4: buf1 -> y4 (overlays dead buf2)
  k_conv4<<<NS_ / 256, 256, 0, stream>>>(buf1, ssAB + 32, w4, b4, y4, part);
  k_stats<<<1, 256, 0, stream>>>(part, NS_ / 256, 1, g4, be4, ssAB + 48);

  k_final<<<NPIX / 4, 256, 0, stream>>>(x0c, y4, ssAB + 48, ydb, pmax);
  k_maxred<<<1, 256, 0, stream>>>(pmax, NPIX / 4, gmax);
  k_sub<<<NPIX / 256, 256, 0, stream>>>(ydb, gmax, (float*)d_out);
}